// Round 17
// baseline (616.582 us; speedup 1.0000x reference)
//
#include <hip/hip_runtime.h>
#include <hip/hip_bf16.h>

#define B_ 4
#define N_ 2048
#define D_ 1024
#define H_ 16
#define HD_ 64
#define MTOT (B_*N_)   // 8192
#define CH_ 16         // scan chunk size
#define NCH_ (N_/CH_)  // 128

typedef __attribute__((ext_vector_type(8))) short short8v;
typedef __attribute__((ext_vector_type(4))) float f32x4;

// fast sigmoid: raw v_rcp_f32 (~1 ulp)
__device__ __forceinline__ float fsig(float x){
  return __builtin_amdgcn_rcpf(1.0f + __expf(-x));
}

// raw barrier: per-wave LDS drain only (no vmcnt drain -> global prefetches stay in flight)
__device__ __forceinline__ void bar_lgkm(){
  asm volatile("s_waitcnt lgkmcnt(0)" ::: "memory");
  __builtin_amdgcn_sched_barrier(0);
  __builtin_amdgcn_s_barrier();
}

// ---------------- cast x -> bf16 (vectorized) ----------------
__global__ void k_cast_bf16(const float* __restrict__ in, __hip_bfloat16* __restrict__ out, int n4){
  int i = blockIdx.x*256 + threadIdx.x;
  if (i >= n4) return;
  float4 vv = ((const float4*)in)[i];
  __hip_bfloat16 b0 = __float2bfloat16(vv.x), b1 = __float2bfloat16(vv.y),
                 b2 = __float2bfloat16(vv.z), b3 = __float2bfloat16(vv.w);
  ushort4 o;
  o.x = *(const unsigned short*)&b0; o.y = *(const unsigned short*)&b1;
  o.z = *(const unsigned short*)&b2; o.w = *(const unsigned short*)&b3;
  ((ushort4*)out)[i] = o;
}

// ---------------- transpose + cast: out[c][r] = in[r][c] ----------------
__global__ void k_transpose_cast(const float* __restrict__ in, __hip_bfloat16* __restrict__ out,
                                 int R, int C){
  __shared__ float tile[64][65];
  int r0 = blockIdx.y*64, c0 = blockIdx.x*64;
  int tid = threadIdx.x;
  #pragma unroll
  for (int i=0;i<16;i++){ int idx = tid + i*256; int rr = idx>>6, cc = idx&63;
    tile[rr][cc] = in[(size_t)(r0+rr)*C + (c0+cc)]; }
  __syncthreads();
  #pragma unroll
  for (int i=0;i<16;i++){ int idx = tid + i*256; int rr = idx>>6, cc = idx&63;
    out[(size_t)(c0+rr)*R + (r0+cc)] = __float2bfloat16(tile[cc][rr]); }
}

// ---------------- pack gate/lr weights: WgL[128][1024] = [Wg1^T ; Wlr^T ; 0] ----------------
__global__ void k_prep_wgl(const float* __restrict__ Wg1, const float* __restrict__ Wlr,
                           __hip_bfloat16* __restrict__ WgL){
  int idx = blockIdx.x*256 + threadIdx.x;   // 0..131071
  int r = idx >> 10, d = idx & 1023;
  float v = 0.f;
  if (r < 64) v = Wg1[(size_t)d*64 + r];
  else if (r < 80) v = Wlr[(size_t)d*16 + (r-64)];
  WgL[idx] = __float2bfloat16(v);
}

// ---------------- post: proj -> t1 bf16, lr = 0.01*sigmoid ----------------
__global__ void k_post_gl(const float* __restrict__ proj, __hip_bfloat16* __restrict__ t1,
                          float* __restrict__ lrout){
  int m = blockIdx.x*4 + (threadIdx.x>>6);
  int e = threadIdx.x & 63;
  float val = proj[(size_t)m*128 + e];
  t1[(size_t)m*64 + e] = __float2bfloat16(val);
  if (e < 16){
    float s = proj[(size_t)m*128 + 64 + e];
    lrout[(size_t)m*16 + e] = 0.01f*fsig(s);
  }
}

// ---------------- async global->LDS helper ----------------
__device__ __forceinline__ void gl2lds16(const void* g, void* l){
  __builtin_amdgcn_global_load_lds((const __attribute__((address_space(1))) void*)g,
                                   (__attribute__((address_space(3))) void*)l, 16, 0, 0);
}

// ---------------- bf16 MFMA GEMM with global_load_lds staging ----------------
// LAYOUT 0: C[m*N+col] fp32. LAYOUT 2: fused QKV (N=3072) -> bf16 scatter [b][h][t][e].
template<int ACT, int LAYOUT>
__global__ __launch_bounds__(256,2) void k_gemm_bt2(
    const __hip_bfloat16* __restrict__ A, const __hip_bfloat16* __restrict__ BT,
    float* __restrict__ C, int M, int N, int K)
{
  __shared__ short As[128*32];
  __shared__ short Bs[128*32];
  const int n0 = blockIdx.x*128, m0 = blockIdx.y*128;
  const int tid = threadIdx.x, lane = tid & 63, wid = tid >> 6;
  const int wm = wid >> 1, wn = wid & 1;
  const short* Aps = (const short*)A;
  const short* Bps = (const short*)BT;
  f32x4 acc[4][4] = {};
  const int srow = wid*32 + (lane>>2);
  const int scol = (lane&3)*8;
  const size_t aoff0 = (size_t)(m0+srow)*K + scol;
  const size_t boff0 = (size_t)(n0+srow)*K + scol;
  short* lA = As + wid*1024;
  short* lB = Bs + wid*1024;
  const int row = lane & 15, kq = (lane >> 4)*8;
  for (int kk = 0; kk < K; kk += 32) {
    __syncthreads();
    gl2lds16(Aps + aoff0 + kk,                 lA);
    gl2lds16(Aps + aoff0 + (size_t)16*K + kk,  lA + 512);
    gl2lds16(Bps + boff0 + kk,                 lB);
    gl2lds16(Bps + boff0 + (size_t)16*K + kk,  lB + 512);
    __syncthreads();
    short8v af[4], bfr[4];
    #pragma unroll
    for (int i=0;i<4;i++) af[i]  = *(const short8v*)(As + (wm*64 + i*16 + row)*32 + kq);
    #pragma unroll
    for (int j=0;j<4;j++) bfr[j] = *(const short8v*)(Bs + (wn*64 + j*16 + row)*32 + kq);
    #pragma unroll
    for (int i=0;i<4;i++)
      #pragma unroll
      for (int j=0;j<4;j++)
        acc[i][j] = __builtin_amdgcn_mfma_f32_16x16x32_bf16(af[i], bfr[j], acc[i][j], 0, 0, 0);
  }
  #pragma unroll
  for (int i=0;i<4;i++){
    #pragma unroll
    for (int j=0;j<4;j++){
      int col = n0 + wn*64 + j*16 + (lane & 15);
      #pragma unroll
      for (int qq=0; qq<4; ++qq){
        int rowg = m0 + wm*64 + i*16 + (lane>>4)*4 + qq;
        float val = acc[i][j][qq];
        if (LAYOUT==0) {
          if (ACT==1) val = val*fsig(val);
          C[(size_t)rowg*N + col] = val;
        } else {
          const int t3 = col >> 10, cc2 = col & 1023;
          if (t3 < 2) val = val*fsig(val);   // silu on q,k; none on v
          size_t oidx = (size_t)t3*((size_t)MTOT*D_)
                      + ((((size_t)(rowg>>11))*16 + (cc2>>6))*(size_t)N_ + (size_t)(rowg & 2047))*64
                      + (size_t)(cc2 & 63);
          ((__hip_bfloat16*)C)[oidx] = __float2bfloat16(val);
        }
      }
    }
  }
}

// ---------------- helpers for chunked scan ----------------
__device__ __forceinline__ unsigned short bfr16(float x){
  __hip_bfloat16 b = __float2bfloat16(x);
  return *(unsigned short*)&b;
}

// ---------------- chunked fast-weight scan v14: 2 barriers/chunk, reg-resident W ----------------
// wave1 owns W1 master (fp32, frag-aligned regs) -> computes KW1,QW1; wave2 owns W3 ->
// KW3,QW3; wave3 grams; wave0 serial B. Loop: bar -> [B(c) || prefetch+O(c-1)] -> bar ->
// [C(c)+A(c+1) in-wave, no mirror, no third barrier]. Raw lgkm-only barriers (no vmcnt drain).
__global__ __launch_bounds__(256,1) void k_scan14(
    const __hip_bfloat16* __restrict__ q, const __hip_bfloat16* __restrict__ k,
    const __hip_bfloat16* __restrict__ v, const float* __restrict__ lr,
    const float* __restrict__ w1i, const float* __restrict__ w3i,
    float* __restrict__ so)
{
  const int blk = blockIdx.x;            // 0..255
  const int bh  = blk >> 2;              // b*16+h
  const int sl  = blk & 3;               // e-slab
  const int b = bh >> 4, h = bh & 15;
  const int e0 = sl*16;
  const int tid = threadIdx.x, lane = tid & 63, wid = tid >> 6;
  const int tA = lane & 15, g = lane >> 4;
  const int ks8 = g*8;

  __shared__ __align__(16) float KW1e[256], KW3e[256];      // [e][t], swizzled slots
  __shared__ __align__(16) float QW1[2][256], QW3[2][256];  // [par][t][e]
  __shared__ __align__(16) float GKK[256], GQK[2][256];     // [t][s]
  __shared__ __align__(16) float C13[2][512];               // [par][s][e][{c1,c3}]
  __shared__ __align__(16) float kS[2][16][68];             // [par] chunk k rows fp32

  const short* kps = (const short*)(k + (size_t)bh*N_*64);
  const short* qps = (const short*)(q + (size_t)bh*N_*64);
  const __hip_bfloat16* vfb = v + (size_t)bh*N_*64;
  const float* lrp = lr + ((size_t)b*N_)*16 + h;
  float* sob = so + (((size_t)b*N_)*16 + h)*64 + e0;

  // per-wave state (live ranges disjoint across wid branches except loop-carried)
  float wm[2][8];                 // waves1-2: W master, e=tA, d=m*32+g*8+j
  short8v wf0, wf1;               // bf16 frags of wm
  short8v pK0,pK1,pQ0,pQ1;        // current chunk frags (waves1-3)
  short8v nK0,nK1,nQ0,nQ1;        // next chunk frags
  float vvr[16], lrr[16];         // wave0 lanes<16

  float* KWe = (wid==2) ? KW3e : KW1e;

  auto rebuild_frags = [&](){
    short8v r0, r1;
    #pragma unroll
    for (int j=0;j<8;j++){ r0[j]=(short)bfr16(wm[0][j]); r1[j]=(short)bfr16(wm[1][j]); }
    wf0 = r0; wf1 = r1;
  };

  auto store_kS = [&](int buf, short8v K0, short8v K1){
    float kf_[16];
    #pragma unroll
    for (int j2=0;j2<4;j2++){
      unsigned u = ((const unsigned*)&K0)[j2];
      kf_[2*j2]   = __uint_as_float(u << 16);
      kf_[2*j2+1] = __uint_as_float(u & 0xffff0000u);
    }
    #pragma unroll
    for (int j2=0;j2<4;j2++){
      unsigned u = ((const unsigned*)&K1)[j2];
      kf_[8+2*j2]   = __uint_as_float(u << 16);
      kf_[8+2*j2+1] = __uint_as_float(u & 0xffff0000u);
    }
    f32x4 s0 = {kf_[0],kf_[1],kf_[2],kf_[3]};    *(f32x4*)&kS[buf][tA][ks8]      = s0;
    f32x4 s1 = {kf_[4],kf_[5],kf_[6],kf_[7]};    *(f32x4*)&kS[buf][tA][ks8+4]    = s1;
    f32x4 s2 = {kf_[8],kf_[9],kf_[10],kf_[11]};  *(f32x4*)&kS[buf][tA][32+ks8]   = s2;
    f32x4 s3 = {kf_[12],kf_[13],kf_[14],kf_[15]};*(f32x4*)&kS[buf][tA][32+ks8+4] = s3;
  };

  auto do_A = [&](int pbuf, short8v K0, short8v K1, short8v Q0, short8v Q1){
    if (wid==1 || wid==2){
      const int slot = (g*4) ^ (((tA>>1)&3)<<2);
      f32x4 acc = {};
      acc = __builtin_amdgcn_mfma_f32_16x16x32_bf16(K0, wf0, acc, 0,0,0);
      acc = __builtin_amdgcn_mfma_f32_16x16x32_bf16(K1, wf1, acc, 0,0,0);
      *(f32x4*)&KWe[tA*16 + slot] = acc;
      f32x4 ac2 = {};
      ac2 = __builtin_amdgcn_mfma_f32_16x16x32_bf16(Q0, wf0, ac2, 0,0,0);
      ac2 = __builtin_amdgcn_mfma_f32_16x16x32_bf16(Q1, wf1, ac2, 0,0,0);
      float* QW = (wid==1) ? QW1[pbuf] : QW3[pbuf];
      #pragma unroll
      for (int qq=0;qq<4;++qq) QW[(g*4+qq)*16 + tA] = ac2[qq];
    } else if (wid==3){
      f32x4 acc = {};
      acc = __builtin_amdgcn_mfma_f32_16x16x32_bf16(K0, K0, acc, 0,0,0);
      acc = __builtin_amdgcn_mfma_f32_16x16x32_bf16(K1, K1, acc, 0,0,0);
      #pragma unroll
      for (int qq=0;qq<4;++qq) GKK[(g*4+qq)*16 + tA] = acc[qq];
      f32x4 ac2 = {};
      ac2 = __builtin_amdgcn_mfma_f32_16x16x32_bf16(Q0, K0, ac2, 0,0,0);
      ac2 = __builtin_amdgcn_mfma_f32_16x16x32_bf16(Q1, K1, ac2, 0,0,0);
      #pragma unroll
      for (int qq=0;qq<4;++qq) GQK[pbuf][(g*4+qq)*16 + tA] = ac2[qq];
    }
  };

  // ---- init ----
  if (wid==1 || wid==2){
    const float* wp = ((wid==1)? w1i : w3i) + (size_t)h*HD_*HD_ + e0 + tA;
    #pragma unroll
    for (int m=0;m<2;m++)
      #pragma unroll
      for (int j=0;j<8;j++)
        wm[m][j] = wp[(size_t)(m*32 + g*8 + j)*64];
    rebuild_frags();
  }
  if (wid>=1){
    pK0 = *(const short8v*)(kps + (size_t)tA*64 + ks8);
    pK1 = *(const short8v*)(kps + (size_t)tA*64 + 32 + ks8);
    pQ0 = *(const short8v*)(qps + (size_t)tA*64 + ks8);
    pQ1 = *(const short8v*)(qps + (size_t)tA*64 + 32 + ks8);
  } else if (lane < 16){
    #pragma unroll
    for (int t=0;t<CH_;++t){
      vvr[t] = __bfloat162float(vfb[(size_t)t*64 + e0 + lane]);
      lrr[t] = lrp[(size_t)t*16];
    }
  }
  // prologue A(0) -> parity 0
  if (wid==1) store_kS(0, pK0, pK1);
  if (wid>=1) do_A(0, pK0, pK1, pQ0, pQ1);

  #pragma unroll 1
  for (int c = 0; c < NCH_; ++c) {
    const int t0 = c*CH_;
    const int par = c & 1, parn = par ^ 1;
    bar_lgkm();   // bar1: A(c) results visible

    const int tn0 = ((c+1 < NCH_) ? c+1 : c) * CH_;
    if (wid >= 1) {
      // prefetch chunk c+1 frags (stay in flight across barriers)
      nK0 = *(const short8v*)(kps + (size_t)(tn0+tA)*64 + ks8);
      nK1 = *(const short8v*)(kps + (size_t)(tn0+tA)*64 + 32 + ks8);
      nQ0 = *(const short8v*)(qps + (size_t)(tn0+tA)*64 + ks8);
      nQ1 = *(const short8v*)(qps + (size_t)(tn0+tA)*64 + 32 + ks8);
      if (c > 0) {
        const int bt = t0 - CH_;
        const int p0 = tid - 64;        // 0..191
        #pragma unroll
        for (int rep=0; rep<2; ++rep){
          const int pp = p0 + rep*192;
          if (pp < 256){
            const int ot = pp >> 4, oe = pp & 15;
            float o1 = QW1[parn][ot*16+oe], o3 = QW3[parn][ot*16+oe];
            #pragma unroll
            for (int s = 0; s < CH_; ++s) {
              const float gl2 = GQK[parn][ot*16+s];
              const float2 cc = *(const float2*)&C13[parn][(s*16+oe)*2];
              const float gm = (s <= ot) ? gl2 : 0.0f;
              o1 = fmaf(-gm, cc.x, o1);
              o3 = fmaf(-gm, cc.y, o3);
            }
            sob[(size_t)(bt+ot)*(H_*HD_) + oe] = (o1*fsig(o1))*o3;
          }
        }
      }
    } else if (lane < 16) {
      // ---- serial B(c) ----
      float vvn[16], lrn[16];
      #pragma unroll
      for (int t=0;t<CH_;++t){
        vvn[t] = __bfloat162float(vfb[(size_t)(tn0+t)*64 + e0 + lane]);
        lrn[t] = lrp[(size_t)(tn0+t)*16];
      }
      float a1[16], a3[16];
      const int swr = ((lane>>1)&3)<<2;
      #pragma unroll
      for (int i2=0;i2<4;i2++){
        f32x4 x1 = *(const f32x4*)&KW1e[lane*16 + ((i2*4) ^ swr)];
        f32x4 x3 = *(const f32x4*)&KW3e[lane*16 + ((i2*4) ^ swr)];
        a1[i2*4+0]=x1[0]; a1[i2*4+1]=x1[1]; a1[i2*4+2]=x1[2]; a1[i2*4+3]=x1[3];
        a3[i2*4+0]=x3[0]; a3[i2*4+1]=x3[1]; a3[i2*4+2]=x3[2]; a3[i2*4+3]=x3[3];
      }
      f32x4 grow[3][4];
      #pragma unroll
      for (int i2=0;i2<4;i2++){
        grow[0][i2] = *(const f32x4*)&GKK[ 0 + i2*4];
        grow[1][i2] = *(const f32x4*)&GKK[16 + i2*4];
        grow[2][i2] = *(const f32x4*)&GKK[32 + i2*4];
      }
      #pragma unroll
      for (int t = 0; t < CH_; ++t) {
        const float h1 = a1[t], h3 = a3[t];
        const float sg = fsig(h1);
        const float s1 = h1*sg;
        const float er = fmaf(s1, h3, -vvr[t]);
        const float ds = sg*fmaf(h1, 1.0f - sg, 1.0f);
        const float lt = lrr[t];
        float2 cc; cc.x = lt*(er*h3*ds); cc.y = lt*(er*s1);
        *(float2*)&C13[par][(t*16+lane)*2] = cc;
        #pragma unroll
        for (int t2 = t+1; t2 < CH_; ++t2) {
          const float gm = grow[t%3][t2>>2][t2&3];
          a1[t2] = fmaf(-gm, cc.x, a1[t2]);
          a3[t2] = fmaf(-gm, cc.y, a3[t2]);
        }
        if (t + 3 < CH_) {
          #pragma unroll
          for (int i2=0;i2<4;i2++) grow[(t+3)%3][i2] = *(const f32x4*)&GKK[(t+3)*16 + i2*4];
        }
      }
      #pragma unroll
      for (int t=0;t<CH_;++t){ vvr[t]=vvn[t]; lrr[t]=lrn[t]; }
    }
    bar_lgkm();   // bar2: C13[par] visible; all Window LDS reads complete

    if (c+1 < NCH_) {
      if (wid==1 || wid==2){
        // ---- C(c): register W update from kS[par] + C13[par] ----
        const int off = (wid==2) ? 1 : 0;
        #pragma unroll
        for (int s=0;s<CH_;++s){
          const float cs = C13[par][(s*16+tA)*2 + off];
          const f32x4 ka = *(const f32x4*)&kS[par][s][ks8];
          const f32x4 kb = *(const f32x4*)&kS[par][s][ks8+4];
          const f32x4 kc = *(const f32x4*)&kS[par][s][32+ks8];
          const f32x4 kd = *(const f32x4*)&kS[par][s][32+ks8+4];
          wm[0][0]=fmaf(-ka[0],cs,wm[0][0]); wm[0][1]=fmaf(-ka[1],cs,wm[0][1]);
          wm[0][2]=fmaf(-ka[2],cs,wm[0][2]); wm[0][3]=fmaf(-ka[3],cs,wm[0][3]);
          wm[0][4]=fmaf(-kb[0],cs,wm[0][4]); wm[0][5]=fmaf(-kb[1],cs,wm[0][5]);
          wm[0][6]=fmaf(-kb[2],cs,wm[0][6]); wm[0][7]=fmaf(-kb[3],cs,wm[0][7]);
          wm[1][0]=fmaf(-kc[0],cs,wm[1][0]); wm[1][1]=fmaf(-kc[1],cs,wm[1][1]);
          wm[1][2]=fmaf(-kc[2],cs,wm[1][2]); wm[1][3]=fmaf(-kc[3],cs,wm[1][3]);
          wm[1][4]=fmaf(-kd[0],cs,wm[1][4]); wm[1][5]=fmaf(-kd[1],cs,wm[1][5]);
          wm[1][6]=fmaf(-kd[2],cs,wm[1][6]); wm[1][7]=fmaf(-kd[3],cs,wm[1][7]);
        }
        rebuild_frags();
        if (wid==1) store_kS(parn, nK0, nK1);
        do_A(parn, nK0, nK1, nQ0, nQ1);   // A(c+1) from registers, no barrier needed
      } else if (wid==3){
        do_A(parn, nK0, nK1, nQ0, nQ1);
      }
    }
  }

  // ---- epilogue: O for the final chunk (parity 1) ----
  if (wid >= 1) {
    const int parp = (NCH_-1) & 1;
    const int bt = (NCH_-1)*CH_;
    const int p0 = tid - 64;
    #pragma unroll
    for (int rep=0; rep<2; ++rep){
      const int pp = p0 + rep*192;
      if (pp < 256){
        const int ot = pp >> 4, oe = pp & 15;
        float o1 = QW1[parp][ot*16+oe], o3 = QW3[parp][ot*16+oe];
        #pragma unroll
        for (int s = 0; s < CH_; ++s) {
          const float gl2 = GQK[parp][ot*16+s];
          const float2 cc = *(const float2*)&C13[parp][(s*16+oe)*2];
          const float gm = (s <= ot) ? gl2 : 0.0f;
          o1 = fmaf(-gm, cc.x, o1);
          o3 = fmaf(-gm, cc.y, o3);
        }
        sob[(size_t)(bt+ot)*(H_*HD_) + oe] = (o1*fsig(o1))*o3;
      }
    }
  }
}

// ---------------- grouped RMSNorm * norm_w * sigmoid(gate) -> bf16 y ----------------
__global__ void k_norm_gate(const float* __restrict__ so, const float* __restrict__ gate,
                            const float* __restrict__ nw, __hip_bfloat16* __restrict__ y)
{
  int idx = blockIdx.x*4 + (threadIdx.x>>6);  // (b*N+t)*16+h
  int e = threadIdx.x & 63;
  float o = so[(size_t)idx*64 + e];
  float ss = o*o;
  #pragma unroll
  for (int m=32; m>=1; m>>=1) ss += __shfl_xor(ss, m, 64);
  float rms = rsqrtf(ss*(1.0f/64.0f) + 1e-6f);
  int hh = idx & 15;
  size_t bn = (size_t)(idx >> 4);
  int d = hh*64 + e;
  float g = gate[bn*1024 + d];
  float val = o*rms*nw[d] * fsig(g);
  y[bn*1024 + d] = __float2bfloat16(val);
}

extern "C" void kernel_launch(void* const* d_in, const int* in_sizes, int n_in,
                              void* d_out, int out_size, void* d_ws, size_t ws_size,
                              hipStream_t stream)
{
  const float* x   = (const float*)d_in[0];
  const float* Wq  = (const float*)d_in[1];
  const float* Wk  = (const float*)d_in[2];
  const float* Wv  = (const float*)d_in[3];
  const float* Wo  = (const float*)d_in[4];
  const float* w1i = (const float*)d_in[5];
  const float* w3i = (const float*)d_in[6];
  const float* Wlr = (const float*)d_in[7];
  const float* nw  = (const float*)d_in[8];
  const float* Wg1 = (const float*)d_in[9];
  const float* Wg2 = (const float*)d_in[10];
  float* out = (float*)d_out;

  char* p = (char*)d_ws;
  auto take = [&](size_t bytes)->void*{ void* r = (void*)p; p += (bytes + 255) & ~(size_t)255; return r; };
  __hip_bfloat16* xb    = (__hip_bfloat16*)take((size_t)MTOT*D_*2);
  __hip_bfloat16* WqkvT = (__hip_bfloat16*)take((size_t)3*D_*D_*2);   // [Wq^T ; Wk^T ; Wv^T]
  __hip_bfloat16* Wot   = (__hip_bfloat16*)take((size_t)D_*D_*2);
  __hip_bfloat16* Wg2t  = (__hip_bfloat16*)take((size_t)D_*HD_*2);
  __hip_bfloat16* WgL   = (__hip_bfloat16*)take((size_t)128*D_*2);
  __hip_bfloat16* t1b   = (__hip_bfloat16*)take((size_t)MTOT*HD_*2);
  float* projt = (float*)take((size_t)MTOT*128*4);
  __hip_bfloat16* qb = (__hip_bfloat16*)take((size_t)MTOT*D_*2);  // q,k,v contiguous bf16
  __hip_bfloat16* kb = (__hip_bfloat16*)take((size_t)MTOT*D_*2);
  __hip_bfloat16* vb = (__hip_bfloat16*)take((size_t)MTOT*D_*2);
  float* lrb = (float*)take((size_t)MTOT*H_*4);
  float* sob = (float*)take((size_t)MTOT*D_*4);
  __hip_bfloat16* yb = (__hip_bfloat16*)take((size_t)MTOT*D_*2);

  k_cast_bf16<<<MTOT*D_/4/256, 256, 0, stream>>>(x, xb, MTOT*D_/4);
  k_transpose_cast<<<dim3(16,16), 256, 0, stream>>>(Wq, WqkvT,             D_, D_);
  k_transpose_cast<<<dim3(16,16), 256, 0, stream>>>(Wk, WqkvT + D_*D_,     D_, D_);
  k_transpose_cast<<<dim3(16,16), 256, 0, stream>>>(Wv, WqkvT + 2*D_*D_,   D_, D_);
  k_transpose_cast<<<dim3(16,16), 256, 0, stream>>>(Wo, Wot, D_, D_);
  k_transpose_cast<<<dim3(16,1),  256, 0, stream>>>(Wg2, Wg2t, HD_, D_);
  k_prep_wgl<<<512, 256, 0, stream>>>(Wg1, Wlr, WgL);
  // gate bottleneck + lr head in one GEMM: proj = x @ [Wg1 | Wlr | 0]
  k_gemm_bt2<0,0><<<dim3(1,64), 256, 0, stream>>>(xb, WgL, projt, MTOT, 128, D_);
  k_post_gl<<<MTOT/4, 256, 0, stream>>>(projt, t1b, lrb);
  // fused q|k|v projection: one N=3072 GEMM, silu on q,k, bf16 scatter to [b][h][t][e]
  k_gemm_bt2<1,2><<<dim3(24,64), 256, 0, stream>>>(xb, WqkvT, (float*)qb, MTOT, 3*D_, D_);
  // gate pre-activation into d_out (free scratch until final GEMM)
  k_gemm_bt2<0,0><<<dim3(8,64), 256, 0, stream>>>(t1b, Wg2t, out, MTOT, D_, HD_);
  k_scan14<<<256, 256, 0, stream>>>(qb, kb, vb, lrb, w1i, w3i, sob);
  k_norm_gate<<<MTOT*H_/4, 256, 0, stream>>>(sob, out, nw, yb);
  k_gemm_bt2<0,0><<<dim3(8,64), 256, 0, stream>>>(yb, Wot, out, MTOT, D_, D_);
}

// Round 18
// 496.253 us; speedup vs baseline: 1.2425x; 1.2425x over previous
//
#include <hip/hip_runtime.h>
#include <hip/hip_bf16.h>

#define B_ 4
#define N_ 2048
#define D_ 1024
#define H_ 16
#define HD_ 64
#define MTOT (B_*N_)   // 8192
#define CH_ 16         // scan chunk size
#define NCH_ (N_/CH_)  // 128

typedef __attribute__((ext_vector_type(8))) short short8v;
typedef __attribute__((ext_vector_type(4))) float f32x4;

// fast sigmoid: raw v_rcp_f32 (~1 ulp), avoids IEEE div sequence on the serial chain
__device__ __forceinline__ float fsig(float x){
  return __builtin_amdgcn_rcpf(1.0f + __expf(-x));
}

// raw barrier: per-wave LDS drain only (no vmcnt drain; global loads keep flying)
__device__ __forceinline__ void bar_lgkm(){
  asm volatile("s_waitcnt lgkmcnt(0)" ::: "memory");
  __builtin_amdgcn_sched_barrier(0);
  __builtin_amdgcn_s_barrier();
}

// ---------------- cast x -> bf16 (vectorized) ----------------
__global__ void k_cast_bf16(const float* __restrict__ in, __hip_bfloat16* __restrict__ out, int n4){
  int i = blockIdx.x*256 + threadIdx.x;
  if (i >= n4) return;
  float4 vv = ((const float4*)in)[i];
  __hip_bfloat16 b0 = __float2bfloat16(vv.x), b1 = __float2bfloat16(vv.y),
                 b2 = __float2bfloat16(vv.z), b3 = __float2bfloat16(vv.w);
  ushort4 o;
  o.x = *(const unsigned short*)&b0; o.y = *(const unsigned short*)&b1;
  o.z = *(const unsigned short*)&b2; o.w = *(const unsigned short*)&b3;
  ((ushort4*)out)[i] = o;
}

// ---------------- 4x transpose + cast in one launch: dst[z][c][r] = src_z[r][c] ----------------
__global__ void k_transpose4(const float* __restrict__ W0, const float* __restrict__ W1,
                             const float* __restrict__ W2, const float* __restrict__ W3,
                             __hip_bfloat16* __restrict__ dst){
  __shared__ float tile[64][65];
  const float* srcs[4] = {W0, W1, W2, W3};
  const float* in = srcs[blockIdx.z];
  __hip_bfloat16* out = dst + (size_t)blockIdx.z*D_*D_;
  int r0 = blockIdx.y*64, c0 = blockIdx.x*64;
  int tid = threadIdx.x;
  #pragma unroll
  for (int i=0;i<16;i++){ int idx = tid + i*256; int rr = idx>>6, cc = idx&63;
    tile[rr][cc] = in[(size_t)(r0+rr)*D_ + (c0+cc)]; }
  __syncthreads();
  #pragma unroll
  for (int i=0;i<16;i++){ int idx = tid + i*256; int rr = idx>>6, cc = idx&63;
    out[(size_t)(c0+rr)*D_ + (r0+cc)] = __float2bfloat16(tile[cc][rr]); }
}

// ---------------- transpose + cast: out[c][r] = in[r][c] ----------------
__global__ void k_transpose_cast(const float* __restrict__ in, __hip_bfloat16* __restrict__ out,
                                 int R, int C){
  __shared__ float tile[64][65];
  int r0 = blockIdx.y*64, c0 = blockIdx.x*64;
  int tid = threadIdx.x;
  #pragma unroll
  for (int i=0;i<16;i++){ int idx = tid + i*256; int rr = idx>>6, cc = idx&63;
    tile[rr][cc] = in[(size_t)(r0+rr)*C + (c0+cc)]; }
  __syncthreads();
  #pragma unroll
  for (int i=0;i<16;i++){ int idx = tid + i*256; int rr = idx>>6, cc = idx&63;
    out[(size_t)(c0+rr)*R + (r0+cc)] = __float2bfloat16(tile[cc][rr]); }
}

// ---------------- pack gate/lr weights: WgL[128][1024] = [Wg1^T ; Wlr^T ; 0] ----------------
__global__ void k_prep_wgl(const float* __restrict__ Wg1, const float* __restrict__ Wlr,
                           __hip_bfloat16* __restrict__ WgL){
  int idx = blockIdx.x*256 + threadIdx.x;   // 0..131071
  int r = idx >> 10, d = idx & 1023;
  float v = 0.f;
  if (r < 64) v = Wg1[(size_t)d*64 + r];
  else if (r < 80) v = Wlr[(size_t)d*16 + (r-64)];
  WgL[idx] = __float2bfloat16(v);
}

// ---------------- post: proj[8192][128] -> t1 bf16 (cols 0-63), lr = 0.01*sigmoid (cols 64-79) ----
__global__ void k_post_gl(const float* __restrict__ proj, __hip_bfloat16* __restrict__ t1,
                          float* __restrict__ lrout){
  int m = blockIdx.x*4 + (threadIdx.x>>6);
  int e = threadIdx.x & 63;
  float val = proj[(size_t)m*128 + e];
  t1[(size_t)m*64 + e] = __float2bfloat16(val);
  if (e < 16){
    float s = proj[(size_t)m*128 + 64 + e];
    lrout[(size_t)m*16 + e] = 0.01f*fsig(s);
  }
}

// ---------------- async global->LDS helper (16B per lane, dest = base + lane*16) ----------------
__device__ __forceinline__ void gl2lds16(const void* g, void* l){
  __builtin_amdgcn_global_load_lds((const __attribute__((address_space(1))) void*)g,
                                   (__attribute__((address_space(3))) void*)l, 16, 0, 0);
}

// ---------------- bf16 MFMA GEMM with global_load_lds staging ----------------
// LAYOUT 0: C[m*N+col] fp32. LAYOUT 2: fused QKV (N=3072) -> bf16 scatter [b][h][t][e],
// silu on q,k (t3<2).
template<int ACT, int LAYOUT>
__global__ __launch_bounds__(256,2) void k_gemm_bt2(
    const __hip_bfloat16* __restrict__ A, const __hip_bfloat16* __restrict__ BT,
    float* __restrict__ C, int M, int N, int K)
{
  __shared__ short As[128*32];
  __shared__ short Bs[128*32];
  const int n0 = blockIdx.x*128, m0 = blockIdx.y*128;
  const int tid = threadIdx.x, lane = tid & 63, wid = tid >> 6;
  const int wm = wid >> 1, wn = wid & 1;
  const short* Aps = (const short*)A;
  const short* Bps = (const short*)BT;
  f32x4 acc[4][4] = {};
  const int srow = wid*32 + (lane>>2);
  const int scol = (lane&3)*8;
  const size_t aoff0 = (size_t)(m0+srow)*K + scol;
  const size_t boff0 = (size_t)(n0+srow)*K + scol;
  short* lA = As + wid*1024;
  short* lB = Bs + wid*1024;
  const int row = lane & 15, kq = (lane >> 4)*8;
  for (int kk = 0; kk < K; kk += 32) {
    __syncthreads();
    gl2lds16(Aps + aoff0 + kk,                 lA);
    gl2lds16(Aps + aoff0 + (size_t)16*K + kk,  lA + 512);
    gl2lds16(Bps + boff0 + kk,                 lB);
    gl2lds16(Bps + boff0 + (size_t)16*K + kk,  lB + 512);
    __syncthreads();
    short8v af[4], bfr[4];
    #pragma unroll
    for (int i=0;i<4;i++) af[i]  = *(const short8v*)(As + (wm*64 + i*16 + row)*32 + kq);
    #pragma unroll
    for (int j=0;j<4;j++) bfr[j] = *(const short8v*)(Bs + (wn*64 + j*16 + row)*32 + kq);
    #pragma unroll
    for (int i=0;i<4;i++)
      #pragma unroll
      for (int j=0;j<4;j++)
        acc[i][j] = __builtin_amdgcn_mfma_f32_16x16x32_bf16(af[i], bfr[j], acc[i][j], 0, 0, 0);
  }
  #pragma unroll
  for (int i=0;i<4;i++){
    #pragma unroll
    for (int j=0;j<4;j++){
      int col = n0 + wn*64 + j*16 + (lane & 15);
      #pragma unroll
      for (int qq=0; qq<4; ++qq){
        int rowg = m0 + wm*64 + i*16 + (lane>>4)*4 + qq;
        float val = acc[i][j][qq];
        if (LAYOUT==0) {
          if (ACT==1) val = val*fsig(val);
          C[(size_t)rowg*N + col] = val;
        } else {
          const int t3 = col >> 10, cc2 = col & 1023;
          if (t3 < 2) val = val*fsig(val);   // silu on q,k; none on v
          size_t oidx = (size_t)t3*((size_t)MTOT*D_)
                      + ((((size_t)(rowg>>11))*16 + (cc2>>6))*(size_t)N_ + (size_t)(rowg & 2047))*64
                      + (size_t)(cc2 & 63);
          ((__hip_bfloat16*)C)[oidx] = __float2bfloat16(val);
        }
      }
    }
  }
}

// ---------------- helpers for chunked scan ----------------
__device__ __forceinline__ unsigned short bfr16(float x){
  __hip_bfloat16 b = __float2bfloat16(x);
  return *(unsigned short*)&b;
}

// ---------------- chunked fast-weight scan v13 + lgkm-only barriers ----------------
// Champion 3-barrier structure: A (waves1-3 MFMA) -> bar -> [B(c) on wave0 || prefetch +
// O(c-1) on waves1-3] -> bar -> C (all 256) + mirror -> bar. q/k/v consumed as bf16.
__global__ __launch_bounds__(256,1) void k_scan13(
    const __hip_bfloat16* __restrict__ q, const __hip_bfloat16* __restrict__ k,
    const __hip_bfloat16* __restrict__ v, const float* __restrict__ lr,
    const float* __restrict__ w1i, const float* __restrict__ w3i,
    float* __restrict__ so)
{
  const int blk = blockIdx.x;            // 0..255
  const int bh  = blk >> 2;              // b*16+h
  const int sl  = blk & 3;               // e-slab
  const int b = bh >> 4, h = bh & 15;
  const int e0 = sl*16;
  const int tid = threadIdx.x, lane = tid & 63, wid = tid >> 6;
  const int tA = lane & 15, ks8 = (lane >> 4)*8;

  __shared__ __align__(16) __hip_bfloat16 Wb1[16*64];   // mirror [e][d], XOR-swizzled
  __shared__ __align__(16) __hip_bfloat16 Wb3[16*64];
  __shared__ __align__(16) float KW1e[256], KW3e[256];  // [e][t], swizzled 16B slots
  __shared__ __align__(16) float QW1[2][256], QW3[2][256];  // [par][t][e]
  __shared__ __align__(16) float GKK[256];              // [t][s]
  __shared__ __align__(16) float GQK[2][256];           // [par][t][s]
  __shared__ __align__(16) float C13[2][512];           // [par][s][e][{c1,c3}]
  __shared__ __align__(16) float kS[16][68];            // chunk-c k rows fp32 (+4 pad)

  const int we = tid & 15;
  const int wd = (tid >> 4) * 4;
  float w1r[4], w3r[4];
  {
    const float* w1p = w1i + (size_t)h*HD_*HD_ + e0 + we;
    const float* w3p = w3i + (size_t)h*HD_*HD_ + e0 + we;
    #pragma unroll
    for (int j=0;j<4;j++){ w1r[j] = w1p[(size_t)(wd+j)*64]; w3r[j] = w3p[(size_t)(wd+j)*64]; }
  }
  const int mir_off = we*128 + ((wd*2) ^ ((we&7)<<4));  // byte offset, 8B aligned
  auto write_mirrors = [&](){
    uint2 p1, p3;
    p1.x = (unsigned)bfr16(w1r[0]) | ((unsigned)bfr16(w1r[1])<<16);
    p1.y = (unsigned)bfr16(w1r[2]) | ((unsigned)bfr16(w1r[3])<<16);
    p3.x = (unsigned)bfr16(w3r[0]) | ((unsigned)bfr16(w3r[1])<<16);
    p3.y = (unsigned)bfr16(w3r[2]) | ((unsigned)bfr16(w3r[3])<<16);
    *(uint2*)((char*)Wb1 + mir_off) = p1;
    *(uint2*)((char*)Wb3 + mir_off) = p3;
  };
  write_mirrors();

  const short* kps = (const short*)(k + (size_t)bh*N_*64);
  const short* qps = (const short*)(q + (size_t)bh*N_*64);
  const __hip_bfloat16* vfb = v + (size_t)bh*N_*64;
  const float* lrp = lr + ((size_t)b*N_)*16 + h;
  float* sob = so + (((size_t)b*N_)*16 + h)*64 + e0;

  auto mir_read = [&](const __hip_bfloat16* Wm, int m)->short8v{
    return *(const short8v*)((const char*)Wm + tA*128 + (((m*32+ks8)*2) ^ ((tA&7)<<4)));
  };

  short8v pK0, pK1;                // waves1,3: k frags of current A-chunk
  short8v pQ0, pQ1;                // waves2,3: q frags
  float  vvr[16], lrr[16];         // wave0 lanes<16

  if (wid==1 || wid==3){
    pK0 = *(const short8v*)(kps + (size_t)tA*64 + ks8);
    pK1 = *(const short8v*)(kps + (size_t)tA*64 + 32 + ks8);
  }
  if (wid==2 || wid==3){
    pQ0 = *(const short8v*)(qps + (size_t)tA*64 + ks8);
    pQ1 = *(const short8v*)(qps + (size_t)tA*64 + 32 + ks8);
  }
  if (wid==0 && lane < 16) {
    #pragma unroll
    for (int t=0;t<CH_;++t){
      vvr[t] = __bfloat162float(vfb[(size_t)t*64 + e0 + lane]);
      lrr[t] = lrp[(size_t)t*16];
    }
  }
  __syncthreads();

  #pragma unroll 1
  for (int c = 0; c < NCH_; ++c) {
    const int t0 = c*CH_;
    const int par = c & 1;

    // ---- phase A: MFMA products from prefetched bf16 frags (waves 1-3) ----
    if (wid == 1) {
      // stage chunk-c k rows as fp32 for phase C (bf16 -> f32 is a shift)
      float kf_[16];
      #pragma unroll
      for (int j=0;j<4;j++){
        unsigned u = ((const unsigned*)&pK0)[j];
        kf_[2*j]   = __uint_as_float(u << 16);
        kf_[2*j+1] = __uint_as_float(u & 0xffff0000u);
      }
      #pragma unroll
      for (int j=0;j<4;j++){
        unsigned u = ((const unsigned*)&pK1)[j];
        kf_[8+2*j]   = __uint_as_float(u << 16);
        kf_[8+2*j+1] = __uint_as_float(u & 0xffff0000u);
      }
      f32x4 s0 = {kf_[0],kf_[1],kf_[2],kf_[3]};   *(f32x4*)&kS[tA][ks8]      = s0;
      f32x4 s1 = {kf_[4],kf_[5],kf_[6],kf_[7]};   *(f32x4*)&kS[tA][ks8+4]    = s1;
      f32x4 s2 = {kf_[8],kf_[9],kf_[10],kf_[11]}; *(f32x4*)&kS[tA][32+ks8]   = s2;
      f32x4 s3 = {kf_[12],kf_[13],kf_[14],kf_[15]};*(f32x4*)&kS[tA][32+ks8+4]= s3;
      const int slot = (((lane>>4)*4) ^ (((tA>>1)&3)<<2));
      f32x4 acc = {};
      acc = __builtin_amdgcn_mfma_f32_16x16x32_bf16(pK0, mir_read(Wb1,0), acc, 0,0,0);
      acc = __builtin_amdgcn_mfma_f32_16x16x32_bf16(pK1, mir_read(Wb1,1), acc, 0,0,0);
      *(f32x4*)&KW1e[tA*16 + slot] = acc;
      f32x4 ac3 = {};
      ac3 = __builtin_amdgcn_mfma_f32_16x16x32_bf16(pK0, mir_read(Wb3,0), ac3, 0,0,0);
      ac3 = __builtin_amdgcn_mfma_f32_16x16x32_bf16(pK1, mir_read(Wb3,1), ac3, 0,0,0);
      *(f32x4*)&KW3e[tA*16 + slot] = ac3;
    } else if (wid == 2) {
      f32x4 acc = {};
      acc = __builtin_amdgcn_mfma_f32_16x16x32_bf16(pQ0, mir_read(Wb1,0), acc, 0,0,0);
      acc = __builtin_amdgcn_mfma_f32_16x16x32_bf16(pQ1, mir_read(Wb1,1), acc, 0,0,0);
      #pragma unroll
      for (int qq=0;qq<4;++qq) QW1[par][((lane>>4)*4+qq)*16 + tA] = acc[qq];   // t-major
      f32x4 ac3 = {};
      ac3 = __builtin_amdgcn_mfma_f32_16x16x32_bf16(pQ0, mir_read(Wb3,0), ac3, 0,0,0);
      ac3 = __builtin_amdgcn_mfma_f32_16x16x32_bf16(pQ1, mir_read(Wb3,1), ac3, 0,0,0);
      #pragma unroll
      for (int qq=0;qq<4;++qq) QW3[par][((lane>>4)*4+qq)*16 + tA] = ac3[qq];
    } else if (wid == 3) {
      f32x4 acc = {};
      acc = __builtin_amdgcn_mfma_f32_16x16x32_bf16(pK0, pK0, acc, 0,0,0);
      acc = __builtin_amdgcn_mfma_f32_16x16x32_bf16(pK1, pK1, acc, 0,0,0);
      #pragma unroll
      for (int qq=0;qq<4;++qq) GKK[((lane>>4)*4+qq)*16 + tA] = acc[qq];
      f32x4 ac2 = {};
      ac2 = __builtin_amdgcn_mfma_f32_16x16x32_bf16(pQ0, pK0, ac2, 0,0,0);
      ac2 = __builtin_amdgcn_mfma_f32_16x16x32_bf16(pQ1, pK1, ac2, 0,0,0);
      #pragma unroll
      for (int qq=0;qq<4;++qq) GQK[par][((lane>>4)*4+qq)*16 + tA] = ac2[qq];
    }
    bar_lgkm();   // bar1: A results visible

    // ---- phase B window: wave0 serial B(c); waves1-3 prefetch c+1 then O(c-1) ----
    const int tn0 = ((c+1 < NCH_) ? c+1 : c) * CH_;
    if (wid >= 1) {
      if (wid==1 || wid==3){
        pK0 = *(const short8v*)(kps + (size_t)(tn0+tA)*64 + ks8);
        pK1 = *(const short8v*)(kps + (size_t)(tn0+tA)*64 + 32 + ks8);
      }
      if (wid==2 || wid==3){
        pQ0 = *(const short8v*)(qps + (size_t)(tn0+tA)*64 + ks8);
        pQ1 = *(const short8v*)(qps + (size_t)(tn0+tA)*64 + 32 + ks8);
      }
      if (c > 0) {
        const int parp = par ^ 1;
        const int bt = t0 - CH_;
        const int p0 = tid - 64;        // 0..191
        #pragma unroll
        for (int rep=0; rep<2; ++rep){
          const int pp = p0 + rep*192;
          if (pp < 256){
            const int ot = pp >> 4, oe = pp & 15;
            float o1 = QW1[parp][ot*16+oe], o3 = QW3[parp][ot*16+oe];
            #pragma unroll
            for (int s = 0; s < CH_; ++s) {
              const float gl2 = GQK[parp][ot*16+s];
              const float2 cc = *(const float2*)&C13[parp][(s*16+oe)*2];
              const float g = (s <= ot) ? gl2 : 0.0f;
              o1 = fmaf(-g, cc.x, o1);
              o3 = fmaf(-g, cc.y, o3);
            }
            sob[(size_t)(bt+ot)*(H_*HD_) + oe] = (o1*fsig(o1))*o3;
          }
        }
      }
    } else if (lane < 16) {
      // issue c+1 v/lr loads (land during serial B)
      float vvn[16], lrn[16];
      #pragma unroll
      for (int t=0;t<CH_;++t){
        vvn[t] = __bfloat162float(vfb[(size_t)(tn0+t)*64 + e0 + lane]);
        lrn[t] = lrp[(size_t)(tn0+t)*16];
      }
      // preload this lane's KW rows (e = lane) into accumulators (undo slot swizzle)
      float a1[16], a3[16];
      const int swr = ((lane>>1)&3)<<2;
      #pragma unroll
      for (int i2=0;i2<4;i2++){
        f32x4 x1 = *(const f32x4*)&KW1e[lane*16 + ((i2*4) ^ swr)];
        f32x4 x3 = *(const f32x4*)&KW3e[lane*16 + ((i2*4) ^ swr)];
        a1[i2*4+0]=x1[0]; a1[i2*4+1]=x1[1]; a1[i2*4+2]=x1[2]; a1[i2*4+3]=x1[3];
        a3[i2*4+0]=x3[0]; a3[i2*4+1]=x3[1]; a3[i2*4+2]=x3[2]; a3[i2*4+3]=x3[3];
      }
      // GKK row pipeline (row t needed at token t; symmetric so row == column)
      f32x4 grow[3][4];
      #pragma unroll
      for (int i2=0;i2<4;i2++){
        grow[0][i2] = *(const f32x4*)&GKK[ 0 + i2*4];
        grow[1][i2] = *(const f32x4*)&GKK[16 + i2*4];
        grow[2][i2] = *(const f32x4*)&GKK[32 + i2*4];
      }
      #pragma unroll
      for (int t = 0; t < CH_; ++t) {
        const float h1 = a1[t], h3 = a3[t];   // fully corrected by eager updates
        const float sg = fsig(h1);
        const float s1 = h1*sg;
        const float er = fmaf(s1, h3, -vvr[t]);
        const float ds = sg*fmaf(h1, 1.0f - sg, 1.0f);
        const float lt = lrr[t];
        float2 cc; cc.x = lt*(er*h3*ds); cc.y = lt*(er*s1);
        *(float2*)&C13[par][(t*16+lane)*2] = cc;
        // eager: push correction of token t into all future accumulators
        #pragma unroll
        for (int t2 = t+1; t2 < CH_; ++t2) {
          const float g = grow[t%3][t2>>2][t2&3];
          a1[t2] = fmaf(-g, cc.x, a1[t2]);
          a3[t2] = fmaf(-g, cc.y, a3[t2]);
        }
        if (t + 3 < CH_) {   // refill consumed slot with row t+3 (used 3 tokens later)
          #pragma unroll
          for (int i2=0;i2<4;i2++) grow[(t+3)%3][i2] = *(const f32x4*)&GKK[(t+3)*16 + i2*4];
        }
      }
      #pragma unroll
      for (int t=0;t<CH_;++t){ vvr[t]=vvn[t]; lrr[t]=lrn[t]; }
    }
    bar_lgkm();   // bar2: C13[par] visible

    // ---- phase C: rank-16 W update (k rows from LDS) + rewrite mirror ----
    #pragma unroll
    for (int s = 0; s < CH_; ++s) {
      const float2 cc = *(const float2*)&C13[par][(s*16+we)*2];
      const float4 ks = *(const float4*)&kS[s][wd];
      w1r[0] = fmaf(-ks.x, cc.x, w1r[0]); w1r[1] = fmaf(-ks.y, cc.x, w1r[1]);
      w1r[2] = fmaf(-ks.z, cc.x, w1r[2]); w1r[3] = fmaf(-ks.w, cc.x, w1r[3]);
      w3r[0] = fmaf(-ks.x, cc.y, w3r[0]); w3r[1] = fmaf(-ks.y, cc.y, w3r[1]);
      w3r[2] = fmaf(-ks.z, cc.y, w3r[2]); w3r[3] = fmaf(-ks.w, cc.y, w3r[3]);
    }
    write_mirrors();
    bar_lgkm();   // bar3: mirror ready for A(c+1)
  }

  // ---- epilogue: O for the final chunk ----
  if (wid >= 1) {
    const int parp = (NCH_-1) & 1;
    const int bt = (NCH_-1)*CH_;
    const int p0 = tid - 64;
    #pragma unroll
    for (int rep=0; rep<2; ++rep){
      const int pp = p0 + rep*192;
      if (pp < 256){
        const int ot = pp >> 4, oe = pp & 15;
        float o1 = QW1[parp][ot*16+oe], o3 = QW3[parp][ot*16+oe];
        #pragma unroll
        for (int s = 0; s < CH_; ++s) {
          const float gl2 = GQK[parp][ot*16+s];
          const float2 cc = *(const float2*)&C13[parp][(s*16+oe)*2];
          const float g = (s <= ot) ? gl2 : 0.0f;
          o1 = fmaf(-g, cc.x, o1);
          o3 = fmaf(-g, cc.y, o3);
        }
        sob[(size_t)(bt+ot)*(H_*HD_) + oe] = (o1*fsig(o1))*o3;
      }
    }
  }
}

// ---------------- grouped RMSNorm * norm_w * sigmoid(gate) -> bf16 y ----------------
__global__ void k_norm_gate(const float* __restrict__ so, const float* __restrict__ gate,
                            const float* __restrict__ nw, __hip_bfloat16* __restrict__ y)
{
  int idx = blockIdx.x*4 + (threadIdx.x>>6);  // (b*N+t)*16+h
  int e = threadIdx.x & 63;
  float o = so[(size_t)idx*64 + e];
  float ss = o*o;
  #pragma unroll
  for (int m=32; m>=1; m>>=1) ss += __shfl_xor(ss, m, 64);
  float rms = rsqrtf(ss*(1.0f/64.0f) + 1e-6f);
  int hh = idx & 15;
  size_t bn = (size_t)(idx >> 4);
  int d = hh*64 + e;
  float g = gate[bn*1024 + d];
  float val = o*rms*nw[d] * fsig(g);
  y[bn*1024 + d] = __float2bfloat16(val);
}

extern "C" void kernel_launch(void* const* d_in, const int* in_sizes, int n_in,
                              void* d_out, int out_size, void* d_ws, size_t ws_size,
                              hipStream_t stream)
{
  const float* x   = (const float*)d_in[0];
  const float* Wq  = (const float*)d_in[1];
  const float* Wk  = (const float*)d_in[2];
  const float* Wv  = (const float*)d_in[3];
  const float* Wo  = (const float*)d_in[4];
  const float* w1i = (const float*)d_in[5];
  const float* w3i = (const float*)d_in[6];
  const float* Wlr = (const float*)d_in[7];
  const float* nw  = (const float*)d_in[8];
  const float* Wg1 = (const float*)d_in[9];
  const float* Wg2 = (const float*)d_in[10];
  float* out = (float*)d_out;

  char* p = (char*)d_ws;
  auto take = [&](size_t bytes)->void*{ void* r = (void*)p; p += (bytes + 255) & ~(size_t)255; return r; };
  __hip_bfloat16* xb    = (__hip_bfloat16*)take((size_t)MTOT*D_*2);
  __hip_bfloat16* WqkvT = (__hip_bfloat16*)take((size_t)4*D_*D_*2);   // [Wq^T;Wk^T;Wv^T;Wo^T]
  __hip_bfloat16* Wot   = WqkvT + (size_t)3*D_*D_;
  __hip_bfloat16* Wg2t  = (__hip_bfloat16*)take((size_t)D_*HD_*2);
  __hip_bfloat16* WgL   = (__hip_bfloat16*)take((size_t)128*D_*2);
  __hip_bfloat16* t1b   = (__hip_bfloat16*)take((size_t)MTOT*HD_*2);
  float* projt = (float*)take((size_t)MTOT*128*4);
  __hip_bfloat16* qb = (__hip_bfloat16*)take((size_t)MTOT*D_*2);  // q,k,v contiguous bf16
  __hip_bfloat16* kb = (__hip_bfloat16*)take((size_t)MTOT*D_*2);
  __hip_bfloat16* vb = (__hip_bfloat16*)take((size_t)MTOT*D_*2);
  float* lrb = (float*)take((size_t)MTOT*H_*4);
  float* sob = (float*)take((size_t)MTOT*D_*4);
  __hip_bfloat16* yb = (__hip_bfloat16*)take((size_t)MTOT*D_*2);

  k_cast_bf16<<<MTOT*D_/4/256, 256, 0, stream>>>(x, xb, MTOT*D_/4);
  k_transpose4<<<dim3(16,16,4), 256, 0, stream>>>(Wq, Wk, Wv, Wo, WqkvT);
  k_transpose_cast<<<dim3(16,1),  256, 0, stream>>>(Wg2, Wg2t, HD_, D_);
  k_prep_wgl<<<512, 256, 0, stream>>>(Wg1, Wlr, WgL);
  // gate bottleneck + lr head in one GEMM: proj = x @ [Wg1 | Wlr | 0]
  k_gemm_bt2<0,0><<<dim3(1,64), 256, 0, stream>>>(xb, WgL, projt, MTOT, 128, D_);
  k_post_gl<<<MTOT/4, 256, 0, stream>>>(projt, t1b, lrb);
  // fused q|k|v projection: one N=3072 GEMM, silu on q,k, bf16 scatter to [b][h][t][e]
  k_gemm_bt2<1,2><<<dim3(24,64), 256, 0, stream>>>(xb, WqkvT, (float*)qb, MTOT, 3*D_, D_);
  // gate pre-activation into d_out (free scratch until final GEMM)
  k_gemm_bt2<0,0><<<dim3(8,64), 256, 0, stream>>>(t1b, Wg2t, out, MTOT, D_, HD_);
  k_scan13<<<256, 256, 0, stream>>>(qb, kb, vb, lrb, w1i, w3i, sob);
  k_norm_gate<<<MTOT*H_/4, 256, 0, stream>>>(sob, out, nw, yb);
  k_gemm_bt2<0,0><<<dim3(8,64), 256, 0, stream>>>(yb, Wot, out, MTOT, D_, D_);
}